// Round 5
// baseline (298.356 us; speedup 1.0000x reference)
//
#include <hip/hip_runtime.h>

typedef unsigned short u16;
typedef __bf16 bf16x8 __attribute__((ext_vector_type(8)));
typedef float f32x4 __attribute__((ext_vector_type(4)));
typedef unsigned short u16x8 __attribute__((ext_vector_type(8)));

#define NPIX 25088
#define HW 3136

static __device__ __forceinline__ u16 f2bf(float f) {
  // round-to-nearest-even f32 -> bf16 (no NaN/inf in this workload)
  unsigned u = __builtin_bit_cast(unsigned, f);
  return (u16)((u + 0x7fffu + ((u >> 16) & 1u)) >> 16);
}

// ---------------------------------------------------------------------------
// Wpb layout: c-slice-major, PLAIN: element (o,c,d) at c*16384 + o*64 + d.
// mm_kernel's B-fragment global loads read 16 fully-used 64B segments per
// instruction in this layout (no LDS staging, no swizzle needed).
// ---------------------------------------------------------------------------

// ---------------------------------------------------------------------------
// Kernel 1: blocks [0,392)    -> p1 = W1 @ x1, stored fp32 transposed P1T[c][pixel]
//           blocks [392,784)  -> p2 = W2 @ x2, stored bf16 P2b[pixel][d]
//           blocks [784,1296) -> Wp fp32 -> bf16 slice-major copy
// 64 pixels/block, thread (t&63)=pixel-lane, q=t>>6 owns outputs q*16..q*16+15.
// Weights wave-uniform -> scalar loads; x held in VGPRs.
// ---------------------------------------------------------------------------
__global__ __launch_bounds__(256) void proj_kernel(
    const float* __restrict__ x1, const float* __restrict__ x2,
    const float* __restrict__ W1, const float* __restrict__ W2,
    const float* __restrict__ Wp,
    float* __restrict__ P1T, u16* __restrict__ P2b, u16* __restrict__ Wpb)
{
  const int blk = blockIdx.x;
  const int t = threadIdx.x;

  if (blk >= 784) {  // Wp conversion: 512 blocks * 256 thr * 8 elems = 1048576
    const long e = (long)(blk - 784) * 2048 + (long)t * 8;  // [o][c][d] linear
    f32x4 a = *(const f32x4*)(Wp + e);
    f32x4 b = *(const f32x4*)(Wp + e + 4);
    u16x8 v;
    v[0]=f2bf(a[0]); v[1]=f2bf(a[1]); v[2]=f2bf(a[2]); v[3]=f2bf(a[3]);
    v[4]=f2bf(b[0]); v[5]=f2bf(b[1]); v[6]=f2bf(b[2]); v[7]=f2bf(b[3]);
    const int o = (int)(e >> 12);
    const int c = (int)(e >> 6) & 63;
    const int d = (int)e & 63;
    *(u16x8*)(Wpb + c * 16384 + o * 64 + d) = v;
    return;
  }

  const bool isP1 = blk < 392;
  const int pb = isP1 ? blk : blk - 392;
  const float* __restrict__ x = isP1 ? x1 : x2;
  const float* __restrict__ W = isP1 ? W1 : W2;   // wave-uniform rows -> s_load

  const int q = t >> 6;                 // output quarter (uniform per wave)
  const int p = pb * 64 + (t & 63);     // pixel
  const int b = p / HW;
  const int hw = p - b * HW;
  const float* xp = x + (size_t)b * 128 * HW + hw;
  const float* Wq = W + q * 16 * 128;

  float xr[128];
  #pragma unroll
  for (int c = 0; c < 128; ++c) xr[c] = xp[(size_t)c * HW];   // coalesced

  float acc[16];
  #pragma unroll
  for (int j = 0; j < 16; ++j) acc[j] = 0.f;

  #pragma unroll 4
  for (int c = 0; c < 128; ++c) {
    const float xv = xr[c];
    #pragma unroll
    for (int j = 0; j < 16; ++j)
      acc[j] = fmaf(Wq[j * 128 + c], xv, acc[j]);
  }

  if (isP1) {
    #pragma unroll
    for (int j = 0; j < 16; ++j)
      P1T[(size_t)(q * 16 + j) * NPIX + p] = acc[j];   // coalesced per j
  } else {
    u16x8 v0, v1;
    #pragma unroll
    for (int j = 0; j < 8; ++j) { v0[j] = f2bf(acc[j]); v1[j] = f2bf(acc[8 + j]); }
    *(u16x8*)(P2b + (size_t)p * 64 + q * 16)     = v0;
    *(u16x8*)(P2b + (size_t)p * 64 + q * 16 + 8) = v1;
  }
}

// ---------------------------------------------------------------------------
// Kernel 2: GEMM core. Block = 128 pixels x 64 outputs, grid 784 (196 pt x 4 ot),
// 4 waves, wave w owns o in [ot*64+w*16, +16). NO barriers in the c-loop:
// B-fragments direct from global (slice-major, L2-resident), depth-2 register
// prefetch; p1 fp32 from LDS (staged once); S_c scaled by p1 via fmac into acc.
// Output: raw bilinear result as bf16 Praw[pix][o].
// ---------------------------------------------------------------------------
__global__ __launch_bounds__(256, 3) void mm_kernel(
    const float* __restrict__ P1T, const u16* __restrict__ P2b,
    const u16* __restrict__ Wpb, u16* __restrict__ Praw)
{
  __shared__ __align__(16) float P1Ts[64 * 128];   // [c][pix] 32 KB

  const int t = threadIdx.x;
  const int w = t >> 6;
  const int lane = t & 63;
  const int l15 = lane & 15;
  const int l4 = lane >> 4;
  const int pt = blockIdx.x >> 2;
  const int ot = blockIdx.x & 3;
  const int P0 = pt * 128;
  const int o0 = ot * 64 + w * 16;      // wave o-base; lane's col = o0 + l15

  // ---- stage P1 tile [64 c][128 pix] f32 (coalesced, standard LDS pattern)
  #pragma unroll
  for (int j = 0; j < 8; ++j) {
    const int idx = j * 1024 + t * 4;
    const int c = idx >> 7, pix = idx & 127;
    *(f32x4*)&P1Ts[idx] = *(const f32x4*)(P1T + (size_t)c * NPIX + P0 + pix);
  }

  // ---- A fragments direct from global (once): row(pixel)=m*16+l15, k=ks*32+l4*8
  bf16x8 afr[8][2];
  #pragma unroll
  for (int m = 0; m < 8; ++m)
    #pragma unroll
    for (int ks = 0; ks < 2; ++ks)
      afr[m][ks] = __builtin_bit_cast(bf16x8,
          *(const u16x8*)(P2b + (size_t)(P0 + m * 16 + l15) * 64 + ks * 32 + l4 * 8));

  __syncthreads();

  const f32x4 zero4 = {0.f, 0.f, 0.f, 0.f};
  f32x4 acc[8];
  #pragma unroll
  for (int m = 0; m < 8; ++m) acc[m] = zero4;

  // B-fragment lane base: slice c at c*16384; row o0+l15; 16B chunk l4 (+ks*32)
  const u16* wpb = Wpb + (o0 + l15) * 64 + l4 * 8;

  // depth-2 register prefetch (round-4-proven pattern; compiler keeps in regs)
  u16x8 bA0 = *(const u16x8*)(wpb);
  u16x8 bA1 = *(const u16x8*)(wpb + 32);
  u16x8 bB0 = *(const u16x8*)(wpb + 16384);
  u16x8 bB1 = *(const u16x8*)(wpb + 16384 + 32);

  #pragma unroll 2
  for (int c = 0; c < 64; ++c) {
    u16x8 nx0 = bB0, nx1 = bB1;
    if (c < 62) {
      nx0 = *(const u16x8*)(wpb + (c + 2) * 16384);
      nx1 = *(const u16x8*)(wpb + (c + 2) * 16384 + 32);
    }

    f32x4 p1v[8];
    #pragma unroll
    for (int m = 0; m < 8; ++m)
      p1v[m] = *(const f32x4*)&P1Ts[c * 128 + m * 16 + l4 * 4];

    #pragma unroll
    for (int m = 0; m < 8; ++m) {
      f32x4 s = zero4;
      s = __builtin_amdgcn_mfma_f32_16x16x32_bf16(afr[m][0],
            __builtin_bit_cast(bf16x8, bA0), s, 0, 0, 0);
      s = __builtin_amdgcn_mfma_f32_16x16x32_bf16(afr[m][1],
            __builtin_bit_cast(bf16x8, bA1), s, 0, 0, 0);
      #pragma unroll
      for (int r = 0; r < 4; ++r)
        acc[m][r] = fmaf(p1v[m][r], s[r], acc[m][r]);
    }

    bA0 = bB0; bA1 = bB1; bB0 = nx0; bB1 = nx1;
  }

  // ---- store raw bf16 [pix][o]
  #pragma unroll
  for (int m = 0; m < 8; ++m)
    #pragma unroll
    for (int r = 0; r < 4; ++r)
      Praw[(size_t)(P0 + m * 16 + l4 * 4 + r) * 256 + o0 + l15] = f2bf(acc[m][r]);
}

// ---------------------------------------------------------------------------
// Kernel 3: LayerNorm + erf-GELU + NCHW transpose-store. Block = 64 pixels,
// 512 thr (8 waves, wave w owns o in [w*32,+32)). Loads Praw, reuses the
// verified stats/epilogue structure from rounds 1/4.
// ---------------------------------------------------------------------------
__global__ __launch_bounds__(512) void ln_kernel(
    const u16* __restrict__ Praw, const float* __restrict__ gamma,
    const float* __restrict__ beta, float* __restrict__ out)
{
  __shared__ __align__(16) unsigned char smem[37376];
  float* tbuf = (float*)smem;             // [8 w][16][65] f32   (33280 B)
  float* ssum = (float*)(smem + 33280);   // [64 pix][8 w]       (2048 B)
  float* ssq  = (float*)(smem + 35328);   // [64 pix][8 w]       (2048 B)

  const int t = threadIdx.x;
  const int w = t >> 6;
  const int lane = t & 63;
  const int l15 = lane & 15;
  const int l4 = lane >> 4;
  const int P0 = blockIdx.x * 64;

  // ---- load this thread's 32 values (same (pix,o) mapping as mm_kernel MFMA C)
  f32x4 acc[4][2];
  #pragma unroll
  for (int m = 0; m < 4; ++m)
    #pragma unroll
    for (int n = 0; n < 2; ++n)
      #pragma unroll
      for (int r = 0; r < 4; ++r) {
        const unsigned u = Praw[(size_t)(P0 + m * 16 + l4 * 4 + r) * 256
                                + w * 32 + n * 16 + l15];
        acc[m][n][r] = __builtin_bit_cast(float, u << 16);
      }

  // ---- LayerNorm stats: per-lane partials over this wave's 32 o's
  float psum[4][4], psq[4][4];
  #pragma unroll
  for (int m = 0; m < 4; ++m)
    #pragma unroll
    for (int r = 0; r < 4; ++r) {
      float a0 = acc[m][0][r], a1 = acc[m][1][r];
      psum[m][r] = a0 + a1;
      psq[m][r]  = a0 * a0 + a1 * a1;
    }
  #pragma unroll
  for (int mask = 1; mask < 16; mask <<= 1) {
    #pragma unroll
    for (int m = 0; m < 4; ++m)
      #pragma unroll
      for (int r = 0; r < 4; ++r) {
        psum[m][r] += __shfl_xor(psum[m][r], mask);
        psq[m][r]  += __shfl_xor(psq[m][r], mask);
      }
  }
  if (l15 == 0) {
    #pragma unroll
    for (int m = 0; m < 4; ++m)
      #pragma unroll
      for (int r = 0; r < 4; ++r) {
        const int pix = m * 16 + l4 * 4 + r;
        ssum[pix * 8 + w] = psum[m][r];
        ssq[pix * 8 + w]  = psq[m][r];
      }
  }
  __syncthreads();

  float mean[4][4], rstd[4][4];
  #pragma unroll
  for (int m = 0; m < 4; ++m)
    #pragma unroll
    for (int r = 0; r < 4; ++r) {
      const int pix = m * 16 + l4 * 4 + r;
      float s = 0.f, q = 0.f;
      #pragma unroll
      for (int wv = 0; wv < 8; ++wv) { s += ssum[pix * 8 + wv]; q += ssq[pix * 8 + wv]; }
      float mu = s * (1.f / 256.f);
      float var = q * (1.f / 256.f) - mu * mu;
      mean[m][r] = mu;
      rstd[m][r] = rsqrtf(var + 1e-5f);
    }

  const int bidx = P0 / HW;
  const int hw0 = P0 - bidx * HW;
  float gam[2], bet[2];
  #pragma unroll
  for (int n = 0; n < 2; ++n) {
    gam[n] = gamma[w * 32 + n * 16 + l15];
    bet[n] = beta[w * 32 + n * 16 + l15];
  }

  // ---- normalize + erf-GELU + transpose via LDS for coalesced NCHW stores
  #pragma unroll
  for (int n = 0; n < 2; ++n) {
    __syncthreads();
    #pragma unroll
    for (int m = 0; m < 4; ++m)
      #pragma unroll
      for (int r = 0; r < 4; ++r) {
        float v = (acc[m][n][r] - mean[m][r]) * rstd[m][r];
        v = v * gam[n] + bet[n];
        float ge = 0.5f * v * (1.f + erff(v * 0.70710678f));
        tbuf[w * 1040 + l15 * 65 + m * 16 + l4 * 4 + r] = ge;
      }
    __syncthreads();
    #pragma unroll
    for (int row = 0; row < 16; ++row) {
      float v = tbuf[w * 1040 + row * 65 + lane];
      const int o = w * 32 + n * 16 + row;
      out[(long)bidx * 802816 + (long)o * HW + hw0 + lane] = v;
    }
  }
}

// ---------------------------------------------------------------------------
extern "C" void kernel_launch(void* const* d_in, const int* in_sizes, int n_in,
                              void* d_out, int out_size, void* d_ws, size_t ws_size,
                              hipStream_t stream) {
  const float* x1    = (const float*)d_in[0];
  const float* x2    = (const float*)d_in[1];
  const float* W1    = (const float*)d_in[2];
  const float* W2    = (const float*)d_in[3];
  const float* Wp    = (const float*)d_in[4];
  const float* gamma = (const float*)d_in[5];
  const float* beta  = (const float*)d_in[6];
  float* out = (float*)d_out;

  // workspace layout (24.6 MB total)
  float* P1T  = (float*)d_ws;                         // 64 x 25088 f32   = 6,422,528 B
  u16*   P2b  = (u16*)((char*)d_ws + 6422528);        // 25088 x 64 bf16  = 3,211,264 B
  u16*   Wpb  = (u16*)((char*)d_ws + 9633792);        // 64 x 256 x 64    = 2,097,152 B
  u16*   Praw = (u16*)((char*)d_ws + 11730944);       // 25088 x 256 bf16 = 12,845,056 B

  proj_kernel<<<dim3(1296), dim3(256), 0, stream>>>(x1, x2, W1, W2, Wp, P1T, P2b, Wpb);
  mm_kernel<<<dim3(784), dim3(256), 0, stream>>>(P1T, P2b, Wpb, Praw);
  ln_kernel<<<dim3(392), dim3(512), 0, stream>>>(Praw, gamma, beta, out);
}

// Round 6
// 230.748 us; speedup vs baseline: 1.2930x; 1.2930x over previous
//
#include <hip/hip_runtime.h>

typedef unsigned short u16;
typedef __bf16 bf16x8 __attribute__((ext_vector_type(8)));
typedef float f32x4 __attribute__((ext_vector_type(4)));
typedef unsigned short u16x8 __attribute__((ext_vector_type(8)));
typedef unsigned short u16x4 __attribute__((ext_vector_type(4)));

#define NPIX 25088
#define HW 3136

static __device__ __forceinline__ u16 f2bf(float f) {
  // round-to-nearest-even f32 -> bf16 (no NaN/inf in this workload)
  unsigned u = __builtin_bit_cast(unsigned, f);
  return (u16)((u + 0x7fffu + ((u >> 16) & 1u)) >> 16);
}
static __device__ __forceinline__ float bf2f(u16 h) {
  return __builtin_bit_cast(float, ((unsigned)h) << 16);
}

// ---------------------------------------------------------------------------
// prep: blocks [0,512)   Wp f32 [o][c][d] -> Wpb bf16 slice-major [c][o][d]
//       blocks [512,520) W1,W2 f32 [o][c] -> W1b,W2b bf16 (same layout)
// ---------------------------------------------------------------------------
__global__ __launch_bounds__(256) void prep_kernel(
    const float* __restrict__ Wp, const float* __restrict__ W1,
    const float* __restrict__ W2,
    u16* __restrict__ Wpb, u16* __restrict__ W1b, u16* __restrict__ W2b)
{
  const int blk = blockIdx.x;
  const int t = threadIdx.x;

  if (blk < 512) {
    const long e = (long)blk * 2048 + (long)t * 8;   // [o][c][d] linear
    f32x4 a = *(const f32x4*)(Wp + e);
    f32x4 b = *(const f32x4*)(Wp + e + 4);
    u16x8 v;
    v[0]=f2bf(a[0]); v[1]=f2bf(a[1]); v[2]=f2bf(a[2]); v[3]=f2bf(a[3]);
    v[4]=f2bf(b[0]); v[5]=f2bf(b[1]); v[6]=f2bf(b[2]); v[7]=f2bf(b[3]);
    const int o = (int)(e >> 12);
    const int c = (int)(e >> 6) & 63;
    const int d = (int)e & 63;
    *(u16x8*)(Wpb + c * 16384 + o * 64 + d) = v;
  } else {
    const int e = (blk - 512) * 2048 + t * 8;        // 0..16383
    const bool is1 = e < 8192;
    const float* src = is1 ? (W1 + e) : (W2 + e - 8192);
    u16* dst = is1 ? (W1b + e) : (W2b + e - 8192);
    f32x4 a = *(const f32x4*)(src);
    f32x4 b = *(const f32x4*)(src + 4);
    u16x8 v;
    v[0]=f2bf(a[0]); v[1]=f2bf(a[1]); v[2]=f2bf(a[2]); v[3]=f2bf(a[3]);
    v[4]=f2bf(b[0]); v[5]=f2bf(b[1]); v[6]=f2bf(b[2]); v[7]=f2bf(b[3]);
    *(u16x8*)dst = v;
  }
}

// ---------------------------------------------------------------------------
// proj: MFMA projections. Block = 128 px, 4 waves: wave w -> px-half (w>>1),
// branch (w&1): br0 = p1 = x1@W1b^T -> P1b bf16 [mid][px];
//               br1 = p2 = x2@W2b^T -> P2b bf16 [px][d].
// A-frags built on the fly from f32 x (each x value read exactly once).
// ---------------------------------------------------------------------------
__global__ __launch_bounds__(256, 2) void proj_kernel(
    const float* __restrict__ x1, const float* __restrict__ x2,
    const u16* __restrict__ W1b, const u16* __restrict__ W2b,
    u16* __restrict__ P1b, u16* __restrict__ P2b)
{
  const int t = threadIdx.x;
  const int w = t >> 6;
  const int lane = t & 63;
  const int l15 = lane & 15;
  const int l4 = lane >> 4;
  const int h = w >> 1;            // pixel half
  const int br = w & 1;            // branch (wave-uniform)
  const int P0 = blockIdx.x * 128 + h * 64;

  const float* __restrict__ x = br ? x2 : x1;
  const u16* __restrict__ Wb = br ? W2b : W1b;

  // per-m pixel base addresses for A-loads (A rows: px = P0 + m*16 + l15)
  size_t xbase[4];
  #pragma unroll
  for (int m = 0; m < 4; ++m) {
    const int px = P0 + m * 16 + l15;
    const int b = px / HW;
    const int hw = px - b * HW;
    xbase[m] = (size_t)b * 128 * HW + hw;
  }

  const f32x4 zero4 = {0.f, 0.f, 0.f, 0.f};
  f32x4 acc[4][4];
  #pragma unroll
  for (int m = 0; m < 4; ++m)
    #pragma unroll
    for (int n = 0; n < 4; ++n) acc[m][n] = zero4;

  #pragma unroll 1
  for (int ks = 0; ks < 4; ++ks) {
    const int k0 = ks * 32 + l4 * 8;
    bf16x8 afr[4];
    #pragma unroll
    for (int m = 0; m < 4; ++m) {
      u16x8 av;
      #pragma unroll
      for (int j = 0; j < 8; ++j)
        av[j] = f2bf(x[xbase[m] + (size_t)(k0 + j) * HW]);
      afr[m] = __builtin_bit_cast(bf16x8, av);
    }
    bf16x8 bfr[4];
    #pragma unroll
    for (int n = 0; n < 4; ++n)
      bfr[n] = __builtin_bit_cast(bf16x8,
          *(const u16x8*)(Wb + (n * 16 + l15) * 128 + k0));
    #pragma unroll
    for (int m = 0; m < 4; ++m)
      #pragma unroll
      for (int n = 0; n < 4; ++n)
        acc[m][n] = __builtin_amdgcn_mfma_f32_16x16x32_bf16(afr[m], bfr[n],
                                                            acc[m][n], 0, 0, 0);
  }

  if (br == 0) {
    // p1 -> P1b[mid][px]: C elem (px = P0+m*16+l4*4+r, mid = n*16+l15)
    #pragma unroll
    for (int m = 0; m < 4; ++m)
      #pragma unroll
      for (int n = 0; n < 4; ++n) {
        u16x4 v;
        #pragma unroll
        for (int r = 0; r < 4; ++r) v[r] = f2bf(acc[m][n][r]);
        *(u16x4*)(P1b + (size_t)(n * 16 + l15) * NPIX + P0 + m * 16 + l4 * 4) = v;
      }
  } else {
    // p2 -> P2b[px][d]: scatter u16 (16 lanes give packed 32B segments)
    #pragma unroll
    for (int m = 0; m < 4; ++m)
      #pragma unroll
      for (int n = 0; n < 4; ++n)
        #pragma unroll
        for (int r = 0; r < 4; ++r)
          P2b[(size_t)(P0 + m * 16 + l4 * 4 + r) * 64 + n * 16 + l15] =
              f2bf(acc[m][n][r]);
  }
}

// ---------------------------------------------------------------------------
// mm: block = 256 px x 64 o (grid 98 pt x 4 ot), 4 waves, wave w = px w*64..+63,
// ALL 64 o (n=0..3) -> p1 LDS broadcast reads amortized over 4x the outputs.
// c-loop: S_c via MFMA (B-frags direct from L2-resident Wpb, depth-2 register
// prefetch), acc += p1[px][c] * S_c (fp32 fmac). No barriers in the loop.
// Praw bf16 [o][px].
// ---------------------------------------------------------------------------
__global__ __launch_bounds__(256, 2) void mm_kernel(
    const u16* __restrict__ P1b, const u16* __restrict__ P2b,
    const u16* __restrict__ Wpb, u16* __restrict__ Praw)
{
  __shared__ __align__(16) u16 P1s[64 * 256];   // [c][px] bf16, 32 KB

  const int t = threadIdx.x;
  const int w = t >> 6;
  const int lane = t & 63;
  const int l15 = lane & 15;
  const int l4 = lane >> 4;
  const int pt = blockIdx.x >> 2;
  const int ot = blockIdx.x & 3;
  const int P0 = pt * 256;
  const int o0 = ot * 64;

  // ---- stage P1 tile [64 c][256 px] bf16 (coalesced)
  #pragma unroll
  for (int j = 0; j < 8; ++j) {
    const int idx = j * 256 + t;
    const int c = idx >> 5, q = idx & 31;
    *(u16x8*)&P1s[c * 256 + q * 8] =
        *(const u16x8*)(P1b + (size_t)c * NPIX + P0 + q * 8);
  }

  // ---- A fragments (p2) direct from global, once
  bf16x8 afr[4][2];
  #pragma unroll
  for (int m = 0; m < 4; ++m)
    #pragma unroll
    for (int ks = 0; ks < 2; ++ks)
      afr[m][ks] = __builtin_bit_cast(bf16x8,
          *(const u16x8*)(P2b + (size_t)(P0 + w * 64 + m * 16 + l15) * 64
                          + ks * 32 + l4 * 8));

  __syncthreads();

  const f32x4 zero4 = {0.f, 0.f, 0.f, 0.f};
  f32x4 acc[4][4];   // [m][n]
  #pragma unroll
  for (int m = 0; m < 4; ++m)
    #pragma unroll
    for (int n = 0; n < 4; ++n) acc[m][n] = zero4;

  // B-frag base: slice c at c*16384; row o0+n*16+l15; chunk l4*8 (+ks*32)
  const u16* wpb = Wpb + (size_t)(o0 + l15) * 64 + l4 * 8;

  u16x8 bcur[4][2], bnxt[4][2];
  #pragma unroll
  for (int n = 0; n < 4; ++n)
    #pragma unroll
    for (int ks = 0; ks < 2; ++ks)
      bcur[n][ks] = *(const u16x8*)(wpb + n * 1024 + ks * 32);

  #pragma unroll 2
  for (int c = 0; c < 64; ++c) {
    const int cn = (c + 1) & 63;
    #pragma unroll
    for (int n = 0; n < 4; ++n)
      #pragma unroll
      for (int ks = 0; ks < 2; ++ks)
        bnxt[n][ks] = *(const u16x8*)(wpb + cn * 16384 + n * 1024 + ks * 32);

    // p1 broadcast reads: same addr across l15 (free), 4 x ds_read_b64
    float p1f[4][4];
    #pragma unroll
    for (int m = 0; m < 4; ++m) {
      u16x4 pv = *(const u16x4*)&P1s[c * 256 + w * 64 + m * 16 + l4 * 4];
      #pragma unroll
      for (int r = 0; r < 4; ++r) p1f[m][r] = bf2f(pv[r]);
    }

    #pragma unroll
    for (int m = 0; m < 4; ++m)
      #pragma unroll
      for (int n = 0; n < 4; ++n) {
        f32x4 s = zero4;
        s = __builtin_amdgcn_mfma_f32_16x16x32_bf16(afr[m][0],
              __builtin_bit_cast(bf16x8, bcur[n][0]), s, 0, 0, 0);
        s = __builtin_amdgcn_mfma_f32_16x16x32_bf16(afr[m][1],
              __builtin_bit_cast(bf16x8, bcur[n][1]), s, 0, 0, 0);
        #pragma unroll
        for (int r = 0; r < 4; ++r)
          acc[m][n][r] = fmaf(p1f[m][r], s[r], acc[m][n][r]);
      }

    #pragma unroll
    for (int n = 0; n < 4; ++n)
      #pragma unroll
      for (int ks = 0; ks < 2; ++ks)
        bcur[n][ks] = bnxt[n][ks];
  }

  // ---- store Praw bf16 [o][px] (8B stores, 32B segments via l4)
  #pragma unroll
  for (int m = 0; m < 4; ++m)
    #pragma unroll
    for (int n = 0; n < 4; ++n) {
      u16x4 v;
      #pragma unroll
      for (int r = 0; r < 4; ++r) v[r] = f2bf(acc[m][n][r]);
      *(u16x4*)(Praw + (size_t)(o0 + n * 16 + l15) * NPIX
                + P0 + w * 64 + m * 16 + l4 * 4) = v;
    }
}

// ---------------------------------------------------------------------------
// ln: thread-per-pixel LayerNorm + erf-GELU. Block = 64 px x 256 o, 256 thr:
// thread (t&63)=px, (t>>6)=o-quarter. Praw[o][px] column reads are wave-
// coalesced (128B). Two passes (2nd pass L1-resident). No shuffles.
// ---------------------------------------------------------------------------
__global__ __launch_bounds__(256) void ln_kernel(
    const u16* __restrict__ Praw, const float* __restrict__ gamma,
    const float* __restrict__ beta, float* __restrict__ out)
{
  __shared__ float ssum[64 * 4], ssq[64 * 4];

  const int t = threadIdx.x;
  const int pl = t & 63;
  const int oq = t >> 6;
  const int px = blockIdx.x * 64 + pl;

  const u16* pr = Praw + (size_t)(oq * 64) * NPIX + px;

  float sum = 0.f, sq = 0.f;
  #pragma unroll 8
  for (int i = 0; i < 64; ++i) {
    const float v = bf2f(pr[(size_t)i * NPIX]);
    sum += v;
    sq = fmaf(v, v, sq);
  }
  ssum[pl * 4 + oq] = sum;
  ssq[pl * 4 + oq] = sq;
  __syncthreads();

  sum = ssum[pl * 4] + ssum[pl * 4 + 1] + ssum[pl * 4 + 2] + ssum[pl * 4 + 3];
  sq  = ssq[pl * 4]  + ssq[pl * 4 + 1]  + ssq[pl * 4 + 2]  + ssq[pl * 4 + 3];
  const float mu = sum * (1.f / 256.f);
  const float var = sq * (1.f / 256.f) - mu * mu;
  const float rstd = rsqrtf(var + 1e-5f);

  const int bimg = (blockIdx.x * 64) / HW;           // 64 | 3136: no straddle
  const int hw = blockIdx.x * 64 - bimg * HW + pl;
  float* ob = out + (size_t)bimg * 802816 + hw;

  #pragma unroll 4
  for (int i = 0; i < 64; ++i) {
    const int o = oq * 64 + i;
    float v = (bf2f(pr[(size_t)i * NPIX]) - mu) * rstd;
    v = v * gamma[o] + beta[o];
    const float ge = 0.5f * v * (1.f + erff(v * 0.70710678f));
    ob[(size_t)o * HW] = ge;
  }
}

// ---------------------------------------------------------------------------
extern "C" void kernel_launch(void* const* d_in, const int* in_sizes, int n_in,
                              void* d_out, int out_size, void* d_ws, size_t ws_size,
                              hipStream_t stream) {
  const float* x1    = (const float*)d_in[0];
  const float* x2    = (const float*)d_in[1];
  const float* W1    = (const float*)d_in[2];
  const float* W2    = (const float*)d_in[3];
  const float* Wp    = (const float*)d_in[4];
  const float* gamma = (const float*)d_in[5];
  const float* beta  = (const float*)d_in[6];
  float* out = (float*)d_out;

  // workspace layout (21.4 MB)
  u16* P1b  = (u16*)d_ws;                             // 64 x 25088      = 3,211,264 B
  u16* P2b  = (u16*)((char*)d_ws + 3211264);          // 25088 x 64      = 3,211,264 B
  u16* Wpb  = (u16*)((char*)d_ws + 6422528);          // 64 x 256 x 64   = 2,097,152 B
  u16* W1b  = (u16*)((char*)d_ws + 8519680);          // 64 x 128        = 16,384 B
  u16* W2b  = (u16*)((char*)d_ws + 8536064);          // 64 x 128        = 16,384 B
  u16* Praw = (u16*)((char*)d_ws + 8552448);          // 256 x 25088     = 12,845,056 B

  prep_kernel<<<dim3(520), dim3(256), 0, stream>>>(Wp, W1, W2, Wpb, W1b, W2b);
  proj_kernel<<<dim3(196), dim3(256), 0, stream>>>(x1, x2, W1b, W2b, P1b, P2b);
  mm_kernel<<<dim3(392), dim3(256), 0, stream>>>(P1b, P2b, Wpb, Praw);
  ln_kernel<<<dim3(392), dim3(256), 0, stream>>>(Praw, gamma, beta, out);
}

// Round 8
// 175.490 us; speedup vs baseline: 1.7001x; 1.3149x over previous
//
#include <hip/hip_runtime.h>

typedef unsigned short u16;
typedef __bf16 bf16x8 __attribute__((ext_vector_type(8)));
typedef float f32x4 __attribute__((ext_vector_type(4)));
typedef unsigned short u16x8 __attribute__((ext_vector_type(8)));
typedef unsigned short u16x4 __attribute__((ext_vector_type(4)));

#define NPIX 25088
#define HW 3136

static __device__ __forceinline__ u16 f2bf(float f) {
  unsigned u = __builtin_bit_cast(unsigned, f);
  return (u16)((u + 0x7fffu + ((u >> 16) & 1u)) >> 16);
}
static __device__ __forceinline__ float bf2f(u16 h) {
  return __builtin_bit_cast(float, ((unsigned)h) << 16);
}

// ---------------------------------------------------------------------------
// Wpb layout: c-slice-major, XOR-swizzled at 16B granularity (round-4-verified):
//   element (o,c,d), d = j*8+j':  Wpb[c*16384 + o*64 + ((j ^ (o&7))<<3) + j']
// Staging into LDS is a LINEAR 32KB copy (global_load_lds-compatible); the
// swizzle makes mm's B-fragment ds_read_b128 2-way-max bank conflicts (free).
// ---------------------------------------------------------------------------
__global__ __launch_bounds__(256) void prep_kernel(
    const float* __restrict__ Wp, const float* __restrict__ W1,
    const float* __restrict__ W2,
    u16* __restrict__ Wpb, u16* __restrict__ W1b, u16* __restrict__ W2b)
{
  const int blk = blockIdx.x;
  const int t = threadIdx.x;

  if (blk < 512) {
    const long e = (long)blk * 2048 + (long)t * 8;   // [o][c][d] linear
    f32x4 a = *(const f32x4*)(Wp + e);
    f32x4 b = *(const f32x4*)(Wp + e + 4);
    u16x8 v;
    v[0]=f2bf(a[0]); v[1]=f2bf(a[1]); v[2]=f2bf(a[2]); v[3]=f2bf(a[3]);
    v[4]=f2bf(b[0]); v[5]=f2bf(b[1]); v[6]=f2bf(b[2]); v[7]=f2bf(b[3]);
    const int o = (int)(e >> 12);
    const int c = (int)(e >> 6) & 63;
    const int j = (int)(e >> 3) & 7;
    *(u16x8*)(Wpb + c * 16384 + o * 64 + ((j ^ (o & 7)) << 3)) = v;
  } else {
    const int e = (blk - 512) * 2048 + t * 8;        // 0..16383
    const bool is1 = e < 8192;
    const float* src = is1 ? (W1 + e) : (W2 + e - 8192);
    u16* dst = is1 ? (W1b + e) : (W2b + e - 8192);
    f32x4 a = *(const f32x4*)(src);
    f32x4 b = *(const f32x4*)(src + 4);
    u16x8 v;
    v[0]=f2bf(a[0]); v[1]=f2bf(a[1]); v[2]=f2bf(a[2]); v[3]=f2bf(a[3]);
    v[4]=f2bf(b[0]); v[5]=f2bf(b[1]); v[6]=f2bf(b[2]); v[7]=f2bf(b[3]);
    *(u16x8*)dst = v;
  }
}

// ---------------------------------------------------------------------------
// proj: 392 blocks x 128 thr (2 waves). Wave w = branch: w0 -> p1 -> P1b[mid][px],
// w1 -> p2 -> P2b[px][d]. 64 px/block, m=4. MFMA with on-the-fly bf16 A-frags
// (each x value read exactly once, coalesced).
// ---------------------------------------------------------------------------
__global__ __launch_bounds__(128) void proj_kernel(
    const float* __restrict__ x1, const float* __restrict__ x2,
    const u16* __restrict__ W1b, const u16* __restrict__ W2b,
    u16* __restrict__ P1b, u16* __restrict__ P2b)
{
  const int t = threadIdx.x;
  const int br = t >> 6;           // wave = branch
  const int lane = t & 63;
  const int l15 = lane & 15;
  const int l4 = lane >> 4;
  const int P0 = blockIdx.x * 64;

  const float* __restrict__ x = br ? x2 : x1;
  const u16* __restrict__ Wb = br ? W2b : W1b;

  size_t xbase[4];
  #pragma unroll
  for (int m = 0; m < 4; ++m) {
    const int px = P0 + m * 16 + l15;
    const int b = px / HW;
    const int hw = px - b * HW;
    xbase[m] = (size_t)b * 128 * HW + hw;
  }

  const f32x4 zero4 = {0.f, 0.f, 0.f, 0.f};
  f32x4 acc[4][4];
  #pragma unroll
  for (int m = 0; m < 4; ++m)
    #pragma unroll
    for (int n = 0; n < 4; ++n) acc[m][n] = zero4;

  #pragma unroll 1
  for (int ks = 0; ks < 4; ++ks) {
    const int k0 = ks * 32 + l4 * 8;
    bf16x8 afr[4];
    #pragma unroll
    for (int m = 0; m < 4; ++m) {
      u16x8 av;
      #pragma unroll
      for (int j = 0; j < 8; ++j)
        av[j] = f2bf(x[xbase[m] + (size_t)(k0 + j) * HW]);
      afr[m] = __builtin_bit_cast(bf16x8, av);
    }
    bf16x8 bfr[4];
    #pragma unroll
    for (int n = 0; n < 4; ++n)
      bfr[n] = __builtin_bit_cast(bf16x8,
          *(const u16x8*)(Wb + (n * 16 + l15) * 128 + k0));
    #pragma unroll
    for (int m = 0; m < 4; ++m)
      #pragma unroll
      for (int n = 0; n < 4; ++n)
        acc[m][n] = __builtin_amdgcn_mfma_f32_16x16x32_bf16(afr[m], bfr[n],
                                                            acc[m][n], 0, 0, 0);
  }

  if (br == 0) {
    #pragma unroll
    for (int m = 0; m < 4; ++m)
      #pragma unroll
      for (int n = 0; n < 4; ++n) {
        u16x4 v;
        #pragma unroll
        for (int r = 0; r < 4; ++r) v[r] = f2bf(acc[m][n][r]);
        *(u16x4*)(P1b + (size_t)(n * 16 + l15) * NPIX + P0 + m * 16 + l4 * 4) = v;
      }
  } else {
    #pragma unroll
    for (int m = 0; m < 4; ++m)
      #pragma unroll
      for (int n = 0; n < 4; ++n)
        #pragma unroll
        for (int r = 0; r < 4; ++r)
          P2b[(size_t)(P0 + m * 16 + l4 * 4 + r) * 64 + n * 16 + l15] =
              f2bf(acc[m][n][r]);
  }
}

// ---------------------------------------------------------------------------
// mm (fused with LayerNorm+GELU): grid 196, block 512 (8 waves). Block =
// 128 px x ALL 256 o; wave w owns o [w*32,+32) (n=2), all px (m=8).
// c-loop: B slice (32KB) double-buffered in LDS via global_load_lds (issue-
// pinned async DMA, 1 barrier/step, guide-verified 2-phase template);
// S_c via MFMA from swizzled LDS; acc += p1[px,c]*S_c (fp32 fmac, p1 from LDS
// broadcast). Epilogue: cross-wave LN stats, erf-GELU, per-wave LDS transpose,
// coalesced NCHW stores.
// ---------------------------------------------------------------------------
__global__ __launch_bounds__(512, 2) void mm_kernel(
    const u16* __restrict__ P1b, const u16* __restrict__ P2b,
    const u16* __restrict__ Wpb, const float* __restrict__ gamma,
    const float* __restrict__ beta, float* __restrict__ out)
{
  __shared__ __align__(16) unsigned char smem[91136];
  u16*   P1s   = (u16*)smem;                 // [64 c][128 px] bf16   0..16384
  u16*   Bbuf0 = (u16*)(smem + 16384);       // 32KB              16384..49152
  u16*   Bbuf1 = (u16*)(smem + 49152);       // 32KB              49152..81920
  float* ssum  = (float*)(smem + 81920);     // [128 px][8 w]     81920..86016
  float* ssq   = (float*)(smem + 86016);     // [128 px][8 w]     86016..90112
  float* smean = (float*)(smem + 90112);     // [128]             90112..90624
  float* srstd = (float*)(smem + 90624);     // [128]             90624..91136
  // tbuf (epilogue, per-wave) aliases P1s/Bbuf: wave w -> smem + w*8512, f32[16][133]

  const int t = threadIdx.x;
  const int w = t >> 6;
  const int lane = t & 63;
  const int l15 = lane & 15;
  const int l4 = lane >> 4;
  const int P0 = blockIdx.x * 128;

  // ---- stage P1 tile [64][128] bf16 (once)
  {
    const int c = t >> 3, col = (t & 7) * 16;
    *(u16x8*)&P1s[c * 128 + col] =
        *(const u16x8*)(P1b + (size_t)c * NPIX + P0 + col);
    *(u16x8*)&P1s[c * 128 + col + 8] =
        *(const u16x8*)(P1b + (size_t)c * NPIX + P0 + col + 8);
  }

  // ---- A fragments (p2) direct from global, held all loop
  bf16x8 afr[8][2];
  #pragma unroll
  for (int m = 0; m < 8; ++m)
    #pragma unroll
    for (int ks = 0; ks < 2; ++ks)
      afr[m][ks] = __builtin_bit_cast(bf16x8,
          *(const u16x8*)(P2b + (size_t)(P0 + m * 16 + l15) * 64
                          + ks * 32 + l4 * 8));

  // ---- async DMA stage of one 32KB Wp c-slice (linear; wave-uniform LDS base)
#define STAGE(DST, CS) {                                                        \
    const u16* src_ = Wpb + (size_t)(CS) * 16384;                               \
    _Pragma("unroll")                                                           \
    for (int i_ = 0; i_ < 4; ++i_) {                                            \
      const int off_ = (w * 4 + i_) * 512;                                      \
      __builtin_amdgcn_global_load_lds(                                         \
          (const __attribute__((address_space(1))) unsigned*)(src_ + off_ + lane * 8), \
          (__attribute__((address_space(3))) unsigned*)((DST) + off_),          \
          16, 0, 0);                                                            \
    }                                                                           \
  }

  STAGE(Bbuf0, 0);

  // B-frag swizzled LDS offsets (u16 units), constant over the loop
  unsigned bofs[2][2];
  #pragma unroll
  for (int n = 0; n < 2; ++n) {
    const int o = w * 32 + n * 16 + l15;
    #pragma unroll
    for (int ks = 0; ks < 2; ++ks)
      bofs[n][ks] = (unsigned)(o * 64 + (((ks * 4 + l4) ^ (o & 7)) << 3));
  }

  const f32x4 zero4 = {0.f, 0.f, 0.f, 0.f};
  f32x4 acc[8][2];
  #pragma unroll
  for (int m = 0; m < 8; ++m)
    #pragma unroll
    for (int n = 0; n < 2; ++n) acc[m][n] = zero4;

  __syncthreads();   // slice 0 + P1s ready

  #pragma unroll 2
  for (int c = 0; c < 64; ++c) {
    u16* Bc = (c & 1) ? Bbuf1 : Bbuf0;
    if (c < 63) STAGE(((c & 1) ? Bbuf0 : Bbuf1), c + 1);   // prefetch next slice

    bf16x8 bfr[2][2];
    #pragma unroll
    for (int n = 0; n < 2; ++n)
      #pragma unroll
      for (int ks = 0; ks < 2; ++ks)
        bfr[n][ks] = __builtin_bit_cast(bf16x8, *(const u16x8*)&Bc[bofs[n][ks]]);

    float p1f[8][4];
    #pragma unroll
    for (int m = 0; m < 8; ++m) {
      u16x4 pv = *(const u16x4*)&P1s[c * 128 + m * 16 + l4 * 4];
      #pragma unroll
      for (int r = 0; r < 4; ++r) p1f[m][r] = bf2f(pv[r]);
    }

    #pragma unroll
    for (int m = 0; m < 8; ++m)
      #pragma unroll
      for (int n = 0; n < 2; ++n) {
        f32x4 s = zero4;
        s = __builtin_amdgcn_mfma_f32_16x16x32_bf16(afr[m][0], bfr[n][0], s, 0, 0, 0);
        s = __builtin_amdgcn_mfma_f32_16x16x32_bf16(afr[m][1], bfr[n][1], s, 0, 0, 0);
        #pragma unroll
        for (int r = 0; r < 4; ++r)
          acc[m][n][r] = fmaf(p1f[m][r], s[r], acc[m][n][r]);
      }

    __syncthreads();   // drains DMA (vmcnt) + my LDS reads; 1 barrier/step
  }

  // ---- LayerNorm stats: lane partial over its wave's 32 o, xor-reduce l15
  float psum[8][4], psq[8][4];
  #pragma unroll
  for (int m = 0; m < 8; ++m)
    #pragma unroll
    for (int r = 0; r < 4; ++r) {
      float a0 = acc[m][0][r], a1 = acc[m][1][r];
      psum[m][r] = a0 + a1;
      psq[m][r]  = a0 * a0 + a1 * a1;
    }
  #pragma unroll
  for (int mask = 1; mask < 16; mask <<= 1) {
    #pragma unroll
    for (int m = 0; m < 8; ++m)
      #pragma unroll
      for (int r = 0; r < 4; ++r) {
        psum[m][r] += __shfl_xor(psum[m][r], mask);
        psq[m][r]  += __shfl_xor(psq[m][r], mask);
      }
  }
  if (l15 == 0) {
    #pragma unroll
    for (int m = 0; m < 8; ++m)
      #pragma unroll
      for (int r = 0; r < 4; ++r) {
        const int px = m * 16 + l4 * 4 + r;
        ssum[px * 8 + w] = psum[m][r];
        ssq[px * 8 + w]  = psq[m][r];
      }
  }
  __syncthreads();

  // one thread per px computes mean/rstd, broadcast via LDS
  if (t < 128) {
    f32x4 s0 = *(const f32x4*)&ssum[t * 8];
    f32x4 s1 = *(const f32x4*)&ssum[t * 8 + 4];
    f32x4 q0 = *(const f32x4*)&ssq[t * 8];
    f32x4 q1 = *(const f32x4*)&ssq[t * 8 + 4];
    float s = s0[0]+s0[1]+s0[2]+s0[3] + s1[0]+s1[1]+s1[2]+s1[3];
    float q = q0[0]+q0[1]+q0[2]+q0[3] + q1[0]+q1[1]+q1[2]+q1[3];
    float mu = s * (1.f / 256.f);
    float var = q * (1.f / 256.f) - mu * mu;
    smean[t] = mu;
    srstd[t] = rsqrtf(var + 1e-5f);
  }
  __syncthreads();

  f32x4 mean[8], rstd[8];
  #pragma unroll
  for (int m = 0; m < 8; ++m) {
    mean[m] = *(const f32x4*)&smean[m * 16 + l4 * 4];
    rstd[m] = *(const f32x4*)&srstd[m * 16 + l4 * 4];
  }

  // per-lane image/coord bases for the two px-halves
  int bimg[2], hwl[2];
  #pragma unroll
  for (int h = 0; h < 2; ++h) {
    const int pxg = P0 + h * 64 + lane;
    bimg[h] = pxg / HW;
    hwl[h] = pxg - bimg[h] * HW;
  }

  float* tbuf = (float*)(smem + w * 8512);   // f32[16][133], per-wave

  #pragma unroll
  for (int n = 0; n < 2; ++n) {
    const int obase = w * 32 + n * 16;
    const float gam = gamma[obase + l15];
    const float bet = beta[obase + l15];
    __syncthreads();
    #pragma unroll
    for (int m = 0; m < 8; ++m)
      #pragma unroll
      for (int r = 0; r < 4; ++r) {
        float v = (acc[m][n][r] - mean[m][r]) * rstd[m][r];
        v = v * gam + bet;
        const float ge = 0.5f * v * (1.f + erff(v * 0.70710678f));
        tbuf[l15 * 133 + m * 16 + l4 * 4 + r] = ge;
      }
    __syncthreads();
    #pragma unroll
    for (int row = 0; row < 16; ++row) {
      const int o = obase + row;
      #pragma unroll
      for (int h = 0; h < 2; ++h) {
        const float v = tbuf[row * 133 + h * 64 + lane];
        out[(size_t)bimg[h] * 802816 + (size_t)o * HW + hwl[h]] = v;
      }
    }
  }
#undef STAGE
}

// ---------------------------------------------------------------------------
extern "C" void kernel_launch(void* const* d_in, const int* in_sizes, int n_in,
                              void* d_out, int out_size, void* d_ws, size_t ws_size,
                              hipStream_t stream) {
  const float* x1    = (const float*)d_in[0];
  const float* x2    = (const float*)d_in[1];
  const float* W1    = (const float*)d_in[2];
  const float* W2    = (const float*)d_in[3];
  const float* Wp    = (const float*)d_in[4];
  const float* gamma = (const float*)d_in[5];
  const float* beta  = (const float*)d_in[6];
  float* out = (float*)d_out;

  // workspace layout (8.6 MB)
  u16* P1b = (u16*)d_ws;                              // 64 x 25088     = 3,211,264 B
  u16* P2b = (u16*)((char*)d_ws + 3211264);           // 25088 x 64     = 3,211,264 B
  u16* Wpb = (u16*)((char*)d_ws + 6422528);           // 64 x 256 x 64  = 2,097,152 B
  u16* W1b = (u16*)((char*)d_ws + 8519680);           // 16,384 B
  u16* W2b = (u16*)((char*)d_ws + 8536064);           // 16,384 B

  prep_kernel<<<dim3(520), dim3(256), 0, stream>>>(Wp, W1, W2, Wpb, W1b, W2b);
  proj_kernel<<<dim3(392), dim3(128), 0, stream>>>(x1, x2, W1b, W2b, P1b, P2b);
  mm_kernel<<<dim3(196), dim3(512), 0, stream>>>(P1b, P2b, Wpb, gamma, beta, out);
}

// Round 9
// 169.991 us; speedup vs baseline: 1.7551x; 1.0323x over previous
//
#include <hip/hip_runtime.h>

typedef unsigned short u16;
typedef __bf16 bf16x8 __attribute__((ext_vector_type(8)));
typedef float f32x4 __attribute__((ext_vector_type(4)));
typedef unsigned short u16x8 __attribute__((ext_vector_type(8)));
typedef unsigned short u16x4 __attribute__((ext_vector_type(4)));

#define NPIX 25088
#define HW 3136

static __device__ __forceinline__ u16 f2bf(float f) {
  unsigned u = __builtin_bit_cast(unsigned, f);
  return (u16)((u + 0x7fffu + ((u >> 16) & 1u)) >> 16);
}
static __device__ __forceinline__ float bf2f(u16 h) {
  return __builtin_bit_cast(float, ((unsigned)h) << 16);
}

// ---------------------------------------------------------------------------
// Fused prep+proj (one launch, no cross-block dependencies):
//  blocks [0,196):   proj. 256 thr = 4 waves: br=(w&1) picks p1/p2 branch,
//                    h=(w>>1) picks the 64-px half of a 128-px tile.
//                    W1/W2 are read as f32 and cast to bf16 in-register, so
//                    no prep stage is needed for them.
//  blocks [196,708): Wp f32 [o][c][d] -> Wpb bf16 c-slice-major, XOR-swizzled
//                    at 16B granularity: (o,c,d),d=j*8+j' ->
//                    Wpb[c*16384 + o*64 + ((j^(o&7))<<3) + j']
//                    (linear 32KB LDS staging stays DMA-compatible; swizzled
//                    ds_read_b128 B-frags are bank-balanced; round-4/8-verified)
// ---------------------------------------------------------------------------
__global__ __launch_bounds__(256, 2) void prep_proj_kernel(
    const float* __restrict__ x1, const float* __restrict__ x2,
    const float* __restrict__ W1, const float* __restrict__ W2,
    const float* __restrict__ Wp,
    u16* __restrict__ P1b, u16* __restrict__ P2b, u16* __restrict__ Wpb)
{
  const int blk = blockIdx.x;
  const int t = threadIdx.x;

  if (blk >= 196) {  // ---- Wp conversion: 512 blocks * 256 thr * 8 elems
    const long e = (long)(blk - 196) * 2048 + (long)t * 8;  // [o][c][d] linear
    f32x4 a = *(const f32x4*)(Wp + e);
    f32x4 b = *(const f32x4*)(Wp + e + 4);
    u16x8 v;
    v[0]=f2bf(a[0]); v[1]=f2bf(a[1]); v[2]=f2bf(a[2]); v[3]=f2bf(a[3]);
    v[4]=f2bf(b[0]); v[5]=f2bf(b[1]); v[6]=f2bf(b[2]); v[7]=f2bf(b[3]);
    const int o = (int)(e >> 12);
    const int c = (int)(e >> 6) & 63;
    const int j = (int)(e >> 3) & 7;
    *(u16x8*)(Wpb + c * 16384 + o * 64 + ((j ^ (o & 7)) << 3)) = v;
    return;
  }

  // ---- proj
  const int w = t >> 6;
  const int br = w & 1;            // 0 -> p1 (x1,W1), 1 -> p2 (x2,W2)
  const int h = w >> 1;            // px half
  const int lane = t & 63;
  const int l15 = lane & 15;
  const int l4 = lane >> 4;
  const int P0 = blk * 128 + h * 64;

  const float* __restrict__ x = br ? x2 : x1;
  const float* __restrict__ Wf = br ? W2 : W1;   // f32 weights, cast on the fly

  size_t xbase[4];
  #pragma unroll
  for (int m = 0; m < 4; ++m) {
    const int px = P0 + m * 16 + l15;
    const int b = px / HW;
    const int hw = px - b * HW;
    xbase[m] = (size_t)b * 128 * HW + hw;
  }

  const f32x4 zero4 = {0.f, 0.f, 0.f, 0.f};
  f32x4 acc[4][4];
  #pragma unroll
  for (int m = 0; m < 4; ++m)
    #pragma unroll
    for (int n = 0; n < 4; ++n) acc[m][n] = zero4;

  #pragma unroll 1
  for (int ks = 0; ks < 4; ++ks) {
    const int k0 = ks * 32 + l4 * 8;
    bf16x8 afr[4];
    #pragma unroll
    for (int m = 0; m < 4; ++m) {
      u16x8 av;
      #pragma unroll
      for (int j = 0; j < 8; ++j)
        av[j] = f2bf(x[xbase[m] + (size_t)(k0 + j) * HW]);
      afr[m] = __builtin_bit_cast(bf16x8, av);
    }
    bf16x8 bfr[4];
    #pragma unroll
    for (int n = 0; n < 4; ++n) {
      f32x4 w0 = *(const f32x4*)(Wf + (n * 16 + l15) * 128 + k0);
      f32x4 w1 = *(const f32x4*)(Wf + (n * 16 + l15) * 128 + k0 + 4);
      u16x8 bv;
      bv[0]=f2bf(w0[0]); bv[1]=f2bf(w0[1]); bv[2]=f2bf(w0[2]); bv[3]=f2bf(w0[3]);
      bv[4]=f2bf(w1[0]); bv[5]=f2bf(w1[1]); bv[6]=f2bf(w1[2]); bv[7]=f2bf(w1[3]);
      bfr[n] = __builtin_bit_cast(bf16x8, bv);
    }
    #pragma unroll
    for (int m = 0; m < 4; ++m)
      #pragma unroll
      for (int n = 0; n < 4; ++n)
        acc[m][n] = __builtin_amdgcn_mfma_f32_16x16x32_bf16(afr[m], bfr[n],
                                                            acc[m][n], 0, 0, 0);
  }

  if (br == 0) {
    // p1 -> P1b[mid][px]
    #pragma unroll
    for (int m = 0; m < 4; ++m)
      #pragma unroll
      for (int n = 0; n < 4; ++n) {
        u16x4 v;
        #pragma unroll
        for (int r = 0; r < 4; ++r) v[r] = f2bf(acc[m][n][r]);
        *(u16x4*)(P1b + (size_t)(n * 16 + l15) * NPIX + P0 + m * 16 + l4 * 4) = v;
      }
  } else {
    // p2 -> P2b[px][d]
    #pragma unroll
    for (int m = 0; m < 4; ++m)
      #pragma unroll
      for (int n = 0; n < 4; ++n)
        #pragma unroll
        for (int r = 0; r < 4; ++r)
          P2b[(size_t)(P0 + m * 16 + l4 * 4 + r) * 64 + n * 16 + l15] =
              f2bf(acc[m][n][r]);
  }
}

// ---------------------------------------------------------------------------
// mm (fused LayerNorm+GELU): grid 392 (>=256 CUs), block 512 (8 waves).
// Block = 64 px x ALL 256 o; wave w owns o [w*32,+32) (n=2), all px (m=4).
// LDS 78336 B -> 2 blocks/CU; __launch_bounds__(512,4) -> VGPR<=128 ->
// 16 waves/CU. Co-resident blocks have independent barriers: one block's
// DMA (global_load_lds double-buffer, 1 barrier/step) hides under the
// other's MFMA. B-frags from XOR-swizzled LDS (bank-balanced).
// Epilogue: cross-wave LN stats, erf-GELU, per-wave LDS transpose, coalesced
// NCHW stores.
// ---------------------------------------------------------------------------
__global__ __launch_bounds__(512, 4) void mm_kernel(
    const u16* __restrict__ P1b, const u16* __restrict__ P2b,
    const u16* __restrict__ Wpb, const float* __restrict__ gamma,
    const float* __restrict__ beta, float* __restrict__ out)
{
  __shared__ __align__(16) unsigned char smem[78336];
  u16*   P1s   = (u16*)smem;                 // [64 c][64 px] bf16    0..8192
  u16*   Bbuf0 = (u16*)(smem + 8192);        // 32KB               8192..40960
  u16*   Bbuf1 = (u16*)(smem + 40960);       // 32KB              40960..73728
  float* ssum  = (float*)(smem + 73728);     // [64 px][8 w]      73728..75776
  float* ssq   = (float*)(smem + 75776);     // [64 px][8 w]      75776..77824
  float* smean = (float*)(smem + 77824);     // [64]              77824..78080
  float* srstd = (float*)(smem + 78080);     // [64]              78080..78336
  // tbuf (epilogue) aliases P1s/Bbuf: wave w -> smem + w*4160, f32[16][65]

  const int t = threadIdx.x;
  const int w = t >> 6;
  const int lane = t & 63;
  const int l15 = lane & 15;
  const int l4 = lane >> 4;
  const int P0 = blockIdx.x * 64;

  // ---- stage P1 tile [64 c][64 px] bf16 (once): thread t -> c=t>>3, col=(t&7)*8
  *(u16x8*)&P1s[(t >> 3) * 64 + (t & 7) * 8] =
      *(const u16x8*)(P1b + (size_t)(t >> 3) * NPIX + P0 + (t & 7) * 8);

  // ---- A fragments (p2) direct from global, held all loop
  bf16x8 afr[4][2];
  #pragma unroll
  for (int m = 0; m < 4; ++m)
    #pragma unroll
    for (int ks = 0; ks < 2; ++ks)
      afr[m][ks] = __builtin_bit_cast(bf16x8,
          *(const u16x8*)(P2b + (size_t)(P0 + m * 16 + l15) * 64
                          + ks * 32 + l4 * 8));

  // ---- async DMA stage of one 32KB Wp c-slice (linear; wave-uniform LDS base)
#define STAGE(DST, CS) {                                                        \
    const u16* src_ = Wpb + (size_t)(CS) * 16384;                               \
    _Pragma("unroll")                                                           \
    for (int i_ = 0; i_ < 4; ++i_) {                                            \
      const int off_ = (w * 4 + i_) * 512;                                      \
      __builtin_amdgcn_global_load_lds(                                         \
          (const __attribute__((address_space(1))) unsigned*)(src_ + off_ + lane * 8), \
          (__attribute__((address_space(3))) unsigned*)((DST) + off_),          \
          16, 0, 0);                                                            \
    }                                                                           \
  }

  STAGE(Bbuf0, 0);

  // B-frag swizzled LDS offsets (u16 units), constant over the loop
  unsigned bofs[2][2];
  #pragma unroll
  for (int n = 0; n < 2; ++n) {
    const int o = w * 32 + n * 16 + l15;
    #pragma unroll
    for (int ks = 0; ks < 2; ++ks)
      bofs[n][ks] = (unsigned)(o * 64 + (((ks * 4 + l4) ^ (o & 7)) << 3));
  }

  const f32x4 zero4 = {0.f, 0.f, 0.f, 0.f};
  f32x4 acc[4][2];
  #pragma unroll
  for (int m = 0; m < 4; ++m)
    #pragma unroll
    for (int n = 0; n < 2; ++n) acc[m][n] = zero4;

  __syncthreads();   // slice 0 + P1s ready

  #pragma unroll 2
  for (int c = 0; c < 64; ++c) {
    u16* Bc = (c & 1) ? Bbuf1 : Bbuf0;
    if (c < 63) STAGE(((c & 1) ? Bbuf0 : Bbuf1), c + 1);   // prefetch next slice

    bf16x8 bfr[2][2];
    #pragma unroll
    for (int n = 0; n < 2; ++n)
      #pragma unroll
      for (int ks = 0; ks < 2; ++ks)
        bfr[n][ks] = __builtin_bit_cast(bf16x8, *(const u16x8*)&Bc[bofs[n][ks]]);

    float p1f[4][4];
    #pragma unroll
    for (int m = 0; m < 4; ++m) {
      u16x4 pv = *(const u16x4*)&P1s[c * 64 + m * 16 + l4 * 4];
      #pragma unroll
      for (int r = 0; r < 4; ++r) p1f[m][r] = bf2f(pv[r]);
    }

    #pragma unroll
    for (int m = 0; m < 4; ++m)
      #pragma unroll
      for (int n = 0; n < 2; ++n) {
        f32x4 s = zero4;
        s = __builtin_amdgcn_mfma_f32_16x16x32_bf16(afr[m][0], bfr[n][0], s, 0, 0, 0);
        s = __builtin_amdgcn_mfma_f32_16x16x32_bf16(afr[m][1], bfr[n][1], s, 0, 0, 0);
        #pragma unroll
        for (int r = 0; r < 4; ++r)
          acc[m][n][r] = fmaf(p1f[m][r], s[r], acc[m][n][r]);
      }

    __syncthreads();   // drains DMA (vmcnt) + LDS reads; 1 barrier/step
  }

  // ---- LayerNorm stats: lane partial over its wave's 32 o, xor-reduce l15
  float psum[4][4], psq[4][4];
  #pragma unroll
  for (int m = 0; m < 4; ++m)
    #pragma unroll
    for (int r = 0; r < 4; ++r) {
      float a0 = acc[m][0][r], a1 = acc[m][1][r];
      psum[m][r] = a0 + a1;
      psq[m][r]  = a0 * a0 + a1 * a1;
    }
  #pragma unroll
  for (int mask = 1; mask < 16; mask <<= 1) {
    #pragma unroll
    for (int m = 0; m < 4; ++m)
      #pragma unroll
      for (int r = 0; r < 4; ++r) {
        psum[m][r] += __shfl_xor(psum[m][r], mask);
        psq[m][r]  += __shfl_xor(psq[m][r], mask);
      }
  }
  if (l15 == 0) {
    #pragma unroll
    for (int m = 0; m < 4; ++m)
      #pragma unroll
      for (int r = 0; r < 4; ++r) {
        const int px = m * 16 + l4 * 4 + r;
        ssum[px * 8 + w] = psum[m][r];
        ssq[px * 8 + w]  = psq[m][r];
      }
  }
  __syncthreads();

  if (t < 64) {
    f32x4 s0 = *(const f32x4*)&ssum[t * 8];
    f32x4 s1 = *(const f32x4*)&ssum[t * 8 + 4];
    f32x4 q0 = *(const f32x4*)&ssq[t * 8];
    f32x4 q1 = *(const f32x4*)&ssq[t * 8 + 4];
    float s = s0[0]+s0[1]+s0[2]+s0[3] + s1[0]+s1[1]+s1[2]+s1[3];
    float q = q0[0]+q0[1]+q0[2]+q0[3] + q1[0]+q1[1]+q1[2]+q1[3];
    float mu = s * (1.f / 256.f);
    float var = q * (1.f / 256.f) - mu * mu;
    smean[t] = mu;
    srstd[t] = rsqrtf(var + 1e-5f);
  }
  __syncthreads();

  f32x4 mean[4], rstd[4];
  #pragma unroll
  for (int m = 0; m < 4; ++m) {
    mean[m] = *(const f32x4*)&smean[m * 16 + l4 * 4];
    rstd[m] = *(const f32x4*)&srstd[m * 16 + l4 * 4];
  }

  const int pxg = P0 + lane;           // 64 | HW -> no image straddle
  const int bimg = pxg / HW;
  const int hwl = pxg - bimg * HW;

  float* tbuf = (float*)(smem + w * 4160);   // f32[16][65], per-wave

  #pragma unroll
  for (int n = 0; n < 2; ++n) {
    const int obase = w * 32 + n * 16;
    const float gam = gamma[obase + l15];
    const float bet = beta[obase + l15];
    __syncthreads();
    #pragma unroll
    for (int m = 0; m < 4; ++m)
      #pragma unroll
      for (int r = 0; r < 4; ++r) {
        float v = (acc[m][n][r] - mean[m][r]) * rstd[m][r];
        v = v * gam + bet;
        const float ge = 0.5f * v * (1.f + erff(v * 0.70710678f));
        tbuf[l15 * 65 + m * 16 + l4 * 4 + r] = ge;
      }
    __syncthreads();
    #pragma unroll
    for (int row = 0; row < 16; ++row) {
      const int o = obase + row;
      out[(size_t)bimg * 802816 + (size_t)o * HW + hwl] = tbuf[row * 65 + lane];
    }
  }
#undef STAGE
}

// ---------------------------------------------------------------------------
extern "C" void kernel_launch(void* const* d_in, const int* in_sizes, int n_in,
                              void* d_out, int out_size, void* d_ws, size_t ws_size,
                              hipStream_t stream) {
  const float* x1    = (const float*)d_in[0];
  const float* x2    = (const float*)d_in[1];
  const float* W1    = (const float*)d_in[2];
  const float* W2    = (const float*)d_in[3];
  const float* Wp    = (const float*)d_in[4];
  const float* gamma = (const float*)d_in[5];
  const float* beta  = (const float*)d_in[6];
  float* out = (float*)d_out;

  // workspace layout (8.5 MB)
  u16* P1b = (u16*)d_ws;                              // 64 x 25088     = 3,211,264 B
  u16* P2b = (u16*)((char*)d_ws + 3211264);           // 25088 x 64     = 3,211,264 B
  u16* Wpb = (u16*)((char*)d_ws + 6422528);           // 64 x 256 x 64  = 2,097,152 B

  prep_proj_kernel<<<dim3(708), dim3(256), 0, stream>>>(x1, x2, W1, W2, Wp,
                                                        P1b, P2b, Wpb);
  mm_kernel<<<dim3(392), dim3(512), 0, stream>>>(P1b, P2b, Wpb, gamma, beta, out);
}